// Round 2
// baseline (1426.624 us; speedup 1.0000x reference)
//
#include <hip/hip_runtime.h>
#include <hip/hip_bf16.h>
#include <stdint.h>

// Problem constants: B2=8, T=512, H=2048, V=32000; tokens per model = 4096.
#define K_DIM 2048
#define NTOK  4096
#define VOCAB 32000
#define BETA  0.1f

typedef __attribute__((ext_vector_type(8))) short short8;   // 8 bf16 (4 VGPRs)
typedef __attribute__((ext_vector_type(8))) int   int8v;    // 32 fp8 (8 VGPRs)
typedef __attribute__((ext_vector_type(4))) float f32x4;    // 4 fp32 acc

union frag8 { int8v v; struct { int4 lo, hi; } s; };

__device__ __forceinline__ unsigned short f2bf(float f) {
  unsigned u = __float_as_uint(f);
  u += 0x7FFFu + ((u >> 16) & 1u);   // RNE (no NaNs in this data)
  return (unsigned short)(u >> 16);
}

__device__ __forceinline__ void gload_lds16(const void* g, void* l) {
  // 16B per lane, LDS dst = wave-uniform base + lane*16
  __builtin_amdgcn_global_load_lds(
      (const __attribute__((address_space(1))) void*)g,
      (__attribute__((address_space(3))) void*)l, 16, 0, 0);
}

// Counted vmcnt wait (T4): literal immediates only. N<0 -> no wait.
template<int N> __device__ __forceinline__ void vwait() {
  if constexpr (N == 12)      asm volatile("s_waitcnt vmcnt(12)" ::: "memory");
  else if constexpr (N == 6)  asm volatile("s_waitcnt vmcnt(6)"  ::: "memory");
  else if constexpr (N == 0)  asm volatile("s_waitcnt vmcnt(0)"  ::: "memory");
}

// ---- fp32 -> fp8 e4m3 (OCP) conversion: all 4 arrays in one launch ----
__global__ void cvt_all_fp8(const float* __restrict__ x, const float* __restrict__ rx,
                            const float* __restrict__ W, const float* __restrict__ rW,
                            unsigned char* __restrict__ Xb, unsigned char* __restrict__ rXb,
                            unsigned char* __restrict__ Wb, unsigned char* __restrict__ rWb) {
  const int which = blockIdx.y;
  const float* in;
  unsigned char* out;
  int n8;
  if (which == 0)      { in = x;  out = Xb;  n8 = NTOK * K_DIM / 8; }
  else if (which == 1) { in = rx; out = rXb; n8 = NTOK * K_DIM / 8; }
  else if (which == 2) { in = W;  out = Wb;  n8 = VOCAB * K_DIM / 8; }
  else                 { in = rW; out = rWb; n8 = VOCAB * K_DIM / 8; }
  int i = blockIdx.x * blockDim.x + threadIdx.x;
  int stride = gridDim.x * blockDim.x;
  for (; i < n8; i += stride) {
    float4 a = ((const float4*)in)[2 * i];
    float4 b = ((const float4*)in)[2 * i + 1];
    int lo = __builtin_amdgcn_cvt_pk_fp8_f32(a.x, a.y, 0, false);
    lo     = __builtin_amdgcn_cvt_pk_fp8_f32(a.z, a.w, lo, true);
    int hi = __builtin_amdgcn_cvt_pk_fp8_f32(b.x, b.y, 0, false);
    hi     = __builtin_amdgcn_cvt_pk_fp8_f32(b.z, b.w, hi, true);
    ((int2*)out)[i] = make_int2(lo, hi);
  }
}

// ---- fused fp8 GEMM + per-row sum(exp(logit)) — ring-3 counted-vmcnt pipeline ----
// Tile: 256 tokens x 128 vocab, BK=128 fp8 bytes; 8 waves (4x2), 64x64 per wave,
// 4x4 frags of mfma_scale_f32_16x16x128_f8f6f4. LDS: ring of THREE K-tile buffers
// (A 32KB + B 16KB each = 144 KiB) -> prefetch depth 3.
//
// ONE barrier per K-tile t:
//   ds_read frags(tile t, buf[t%3]) -> 16x MFMA -> lgkmcnt(0)
//   -> s_waitcnt vmcnt(6)   (tile t+1's 6 loads landed; tile t+2's stay in flight)
//   -> s_barrier            (all waves done reading tile t AND tile t+1 visible)
//   -> stage tile t+3 into buf[t%3] (just freed; its reads happen 3 iters later,
//      separated by 3 barriers)
// Never vmcnt(0) in the main loop (T4). __syncthreads would emit a vmcnt(0)
// drain before s_barrier -> the m97 ~35% ceiling; raw s_barrier avoids it.
//
// LDS layout per row: 128B = eight 16B chunks, global chunk j stored at
// position j ^ (row&7); staging permutes the per-lane GLOBAL address
// (global_load_lds LDS dst is fixed at base+lane*16). Identical proven
// swizzle/fragment math as the verified 128x128 kernel.
__global__ __launch_bounds__(512, 1)
void gemm_lse_fp8(const unsigned char* __restrict__ A0, const unsigned char* __restrict__ A1,
                  const unsigned char* __restrict__ B0, const unsigned char* __restrict__ B1,
                  float* __restrict__ sumexp) {
  __shared__ unsigned char sm[3 * 49152];   // 144 KiB (<=160 KiB/WG on gfx950)
  const int tid  = threadIdx.x;
  const int lane = tid & 63;
  const int wid  = tid >> 6;      // 0..7
  const int wm   = wid >> 1;      // 0..3: 64-row slice of the 256-token tile
  const int wn   = wid & 1;       // 0..1: 64-col slice of the 128-vocab tile

  // XCD-aware swizzle (T1): 4000 tiles, 4000 % 8 == 0 -> bijective.
  const int d  = blockIdx.x;
  const int w  = (d & 7) * 500 + (d >> 3);
  const int m0 = (w & 15) * 256;            // token tile
  const int n0 = (w >> 4) * 128;            // vocab tile
  const int model = blockIdx.z;
  const unsigned char* __restrict__ Ag = model ? A1 : A0;
  const unsigned char* __restrict__ Bg = model ? B1 : B0;

  unsigned char* sA0 = sm;
  unsigned char* sB0 = sm + 32768;
  unsigned char* sA1 = sm + 49152;
  unsigned char* sB1 = sm + 49152 + 32768;
  unsigned char* sA2 = sm + 98304;
  unsigned char* sB2 = sm + 98304 + 32768;

  f32x4 acc[4][4];
#pragma unroll
  for (int i = 0; i < 4; i++)
#pragma unroll
    for (int j = 0; j < 4; j++) acc[i][j] = (f32x4){0.f, 0.f, 0.f, 0.f};

  // Staging geometry: each 1KB LDS chunk = 8 rows x 128B. Wave `wid` owns
  // chunks {c*8+wid}. Lane covers row (lane>>3), LDS 16B position (lane&7),
  // fetching global chunk j = (lane&7) ^ (row&7).
  const int rsub = lane >> 3;               // 0..7
  const int jsw  = ((lane & 7) ^ rsub) * 16;
  const int q    = lane >> 4;
  const int l15  = lane & 15, l7 = lane & 7;
  const int p0   = ((2 * q)     ^ l7) * 16; // swizzled positions of chunks 2q,2q+1
  const int p1   = ((2 * q + 1) ^ l7) * 16;

  auto stage = [&](int k0, unsigned char* bufA, unsigned char* bufB) {
#pragma unroll
    for (int c = 0; c < 4; ++c) {           // A: 32KB = 32 chunks, 4 per wave
      int cc = c * 8 + wid;
      gload_lds16(Ag + (size_t)(m0 + cc * 8 + rsub) * K_DIM + k0 + jsw, bufA + cc * 1024);
    }
#pragma unroll
    for (int c = 0; c < 2; ++c) {           // B: 16KB = 16 chunks, 2 per wave
      int cc = c * 8 + wid;
      gload_lds16(Bg + (size_t)(n0 + cc * 8 + rsub) * K_DIM + k0 + jsw, bufB + cc * 1024);
    }
  };

#define GBODY(T, SA, SB, DOSTAGE, VMN, HASNEXT)                               \
  do {                                                                        \
    frag8 af[4], bf[4];                                                       \
    _Pragma("unroll") for (int i = 0; i < 4; i++) {                           \
      const unsigned char* rp = SA + (wm * 64 + i * 16 + l15) * 128;          \
      af[i].s.lo = *(const int4*)(rp + p0);                                   \
      af[i].s.hi = *(const int4*)(rp + p1);                                   \
    }                                                                         \
    _Pragma("unroll") for (int j = 0; j < 4; j++) {                           \
      const unsigned char* rp = SB + (wn * 64 + j * 16 + l15) * 128;          \
      bf[j].s.lo = *(const int4*)(rp + p0);                                   \
      bf[j].s.hi = *(const int4*)(rp + p1);                                   \
    }                                                                         \
    __builtin_amdgcn_s_setprio(1);                                            \
    _Pragma("unroll") for (int i = 0; i < 4; i++)                             \
      _Pragma("unroll") for (int j = 0; j < 4; j++)                           \
        acc[i][j] = __builtin_amdgcn_mfma_scale_f32_16x16x128_f8f6f4(         \
            af[i].v, bf[j].v, acc[i][j], 0, 0, 0, 127, 0, 127);               \
    __builtin_amdgcn_s_setprio(0);                                            \
    if (HASNEXT) {                                                            \
      asm volatile("s_waitcnt lgkmcnt(0)" ::: "memory"); /* reads retired */  \
      vwait<VMN>();                       /* tile T+1 landed; T+2 in flight */\
      __builtin_amdgcn_sched_barrier(0);  /* pin ordering (rule #18) */       \
      __builtin_amdgcn_s_barrier();                                           \
      if (DOSTAGE) stage((T + 3) * 128, SA, SB);  /* refill freed buffer */   \
    }                                                                         \
  } while (0)

  // Prologue: fill the 3-deep ring; wait only for tile 0 (18 -> 12 outstanding).
  stage(0,   sA0, sB0);
  stage(128, sA1, sB1);
  stage(256, sA2, sB2);
  vwait<12>();
  __builtin_amdgcn_sched_barrier(0);
  __builtin_amdgcn_s_barrier();

#pragma unroll
  for (int tb = 0; tb < 12; tb += 3) {
    GBODY(tb,     sA0, sB0, 1, 6, 1);
    GBODY(tb + 1, sA1, sB1, 1, 6, 1);
    GBODY(tb + 2, sA2, sB2, 1, 6, 1);
  }
  GBODY(12, sA0, sB0, 1, 6, 1);    // stages tile 15 -> buf0
  GBODY(13, sA1, sB1, 0, 6, 1);    // drain: tile 14 landed, tile 15 in flight
  GBODY(14, sA2, sB2, 0, 0, 1);    // drain: tile 15 landed
  GBODY(15, sA0, sB0, 0, -1, 0);   // last tile: no wait, no barrier
#undef GBODY

  // Epilogue: rs[i][r] = sum over this wave's 64 vocab cols of exp(logit).
  // C/D layout (shape-determined): col = lane&15, row = q*4 + reg.
  float rs[4][4];
#pragma unroll
  for (int i = 0; i < 4; i++)
#pragma unroll
    for (int r = 0; r < 4; r++) rs[i][r] = 0.f;
#pragma unroll
  for (int i = 0; i < 4; i++)
#pragma unroll
    for (int j = 0; j < 4; j++)
#pragma unroll
      for (int r = 0; r < 4; r++) rs[i][r] += __expf(acc[i][j][r]);
#pragma unroll
  for (int i = 0; i < 4; i++)
#pragma unroll
    for (int r = 0; r < 4; r++) {
      float v = rs[i][r];
      v += __shfl_xor(v, 1, 64);
      v += __shfl_xor(v, 2, 64);
      v += __shfl_xor(v, 4, 64);
      v += __shfl_xor(v, 8, 64);
      rs[i][r] = v;
    }
  if ((lane & 15) == 0) {
#pragma unroll
    for (int i = 0; i < 4; i++)
#pragma unroll
      for (int r = 0; r < 4; r++) {
        int row = m0 + wm * 64 + i * 16 + q * 4 + r;
        atomicAdd(&sumexp[model * NTOK + row], rs[i][r]);
      }
  }
}

// ---- fallback fp32-input GEMM (bf16 MFMA, VGPR-staged) — used only if ws
// is too small for the fp8 buffers. Unchanged verified path. ----
__global__ __launch_bounds__(256)
void gemm_lse_f32(const float* __restrict__ A0, const float* __restrict__ A1,
                  const float* __restrict__ B0, const float* __restrict__ B1,
                  float* __restrict__ sumexp) {
  __shared__ unsigned short smA[128 * 64];
  __shared__ unsigned short smB[128 * 64];
  const int tid  = threadIdx.x;
  const int lane = tid & 63;
  const int wid  = tid >> 6;
  const int wm = wid & 1, wn = wid >> 1;
  const int m0 = blockIdx.x * 128;
  const int n0 = blockIdx.y * 128;
  const int model = blockIdx.z;
  const float* Agf = model ? A1 : A0;
  const float* Bgf = model ? B1 : B0;

  f32x4 acc[4][4];
#pragma unroll
  for (int i = 0; i < 4; i++)
#pragma unroll
    for (int j = 0; j < 4; j++) acc[i][j] = (f32x4){0.f, 0.f, 0.f, 0.f};

  for (int k0 = 0; k0 < K_DIM; k0 += 64) {
#pragma unroll
    for (int i = 0; i < 8; i++) {
      int f = tid + i * 256;
      int row = f >> 4, kc = (f & 15) * 4;
      int pos = (((kc >> 3) ^ (row & 7)) << 3) + (kc & 7);  // swizzled
      float4 va = *(const float4*)(Agf + (size_t)(m0 + row) * K_DIM + k0 + kc);
      float4 vb = *(const float4*)(Bgf + (size_t)(n0 + row) * K_DIM + k0 + kc);
      ushort4 ha, hb;
      ha.x = f2bf(va.x); ha.y = f2bf(va.y); ha.z = f2bf(va.z); ha.w = f2bf(va.w);
      hb.x = f2bf(vb.x); hb.y = f2bf(vb.y); hb.z = f2bf(vb.z); hb.w = f2bf(vb.w);
      *(ushort4*)&smA[row * 64 + pos] = ha;
      *(ushort4*)&smB[row * 64 + pos] = hb;
    }
    __syncthreads();
    const int quad = lane >> 4;
    const int l7   = lane & 7;
#pragma unroll
    for (int s = 0; s < 2; s++) {
      short8 af[4], bf[4];
      const int cpos = ((s * 4 + quad) ^ l7) * 8;
#pragma unroll
      for (int i = 0; i < 4; i++)
        af[i] = *(const short8*)&smA[(wm * 64 + i * 16 + (lane & 15)) * 64 + cpos];
#pragma unroll
      for (int j = 0; j < 4; j++)
        bf[j] = *(const short8*)&smB[(wn * 64 + j * 16 + (lane & 15)) * 64 + cpos];
#pragma unroll
      for (int i = 0; i < 4; i++)
#pragma unroll
        for (int j = 0; j < 4; j++)
          acc[i][j] = __builtin_amdgcn_mfma_f32_16x16x32_bf16(af[i], bf[j], acc[i][j], 0, 0, 0);
    }
    __syncthreads();
  }

  float rs[4][4];
#pragma unroll
  for (int i = 0; i < 4; i++)
#pragma unroll
    for (int r = 0; r < 4; r++) rs[i][r] = 0.f;
#pragma unroll
  for (int i = 0; i < 4; i++)
#pragma unroll
    for (int j = 0; j < 4; j++)
#pragma unroll
      for (int r = 0; r < 4; r++) rs[i][r] += __expf(acc[i][j][r]);
#pragma unroll
  for (int i = 0; i < 4; i++)
#pragma unroll
    for (int r = 0; r < 4; r++) {
      float v = rs[i][r];
      v += __shfl_xor(v, 1, 64);
      v += __shfl_xor(v, 2, 64);
      v += __shfl_xor(v, 4, 64);
      v += __shfl_xor(v, 8, 64);
      rs[i][r] = v;
    }
  if ((lane & 15) == 0) {
    int quad = lane >> 4;
#pragma unroll
    for (int i = 0; i < 4; i++)
#pragma unroll
      for (int r = 0; r < 4; r++) {
        int row = m0 + wm * 64 + i * 16 + quad * 4 + r;
        atomicAdd(&sumexp[model * NTOK + row], rs[i][r]);
      }
  }
}

// ---- target logit: one wave per (model, token), fp32 dot over H=2048 ----
__global__ void tgt_kernel(const float* __restrict__ x, const float* __restrict__ rx,
                           const float* __restrict__ W, const float* __restrict__ rW,
                           const int* __restrict__ y, float* __restrict__ tgt) {
  int g = blockIdx.x * blockDim.x + threadIdx.x;
  int gw = g >> 6;           // 0..8191
  int lane = g & 63;
  int model = gw >> 12;
  int token = gw & (NTOK - 1);
  int yi = y[token];
  float s = 0.f;
  if (yi >= 0) {
    const float* xv = (model ? rx : x) + (size_t)token * K_DIM;
    const float* wv = (model ? rW : W) + (size_t)yi * K_DIM;
#pragma unroll
    for (int i = 0; i < 8; i++) {
      int p = (lane + i * 64) * 4;
      float4 a = *(const float4*)(xv + p);
      float4 b = *(const float4*)(wv + p);
      s += a.x * b.x + a.y * b.y + a.z * b.z + a.w * b.w;
    }
  }
  for (int off = 32; off; off >>= 1) s += __shfl_xor(s, off, 64);
  if (lane == 0) tgt[gw] = s;
}

// ---- finalize: logp = tgt - log(sumexp); per-row mean; DPO loss ----
__global__ void finalize(const float* __restrict__ sumexp, const float* __restrict__ tgt,
                         const int* __restrict__ y, float* __restrict__ out) {
  __shared__ float ssum[16];  // [model][row]
  __shared__ int scnt[8];
  if (threadIdx.x < 16) ssum[threadIdx.x] = 0.f;
  if (threadIdx.x < 8) scnt[threadIdx.x] = 0;
  __syncthreads();
  for (int idx = threadIdx.x; idx < 2 * NTOK; idx += blockDim.x) {
    int model = idx >> 12;
    int token = idx & (NTOK - 1);
    int row = token >> 9;     // 512 tokens per sequence
    int yi = y[token];
    if (yi != -100) {
      float v = tgt[idx] - logf(sumexp[idx]);
      atomicAdd(&ssum[model * 8 + row], v);
      if (model == 0) atomicAdd(&scnt[row], 1);
    }
  }
  __syncthreads();
  if (threadIdx.x == 0) {
    float lp[16];
    for (int m = 0; m < 2; m++)
      for (int r = 0; r < 8; r++) {
        int n = scnt[r] > 0 ? scnt[r] : 1;
        lp[m * 8 + r] = ssum[m * 8 + r] / (float)n;
      }
    float loss = 0.f;
    for (int b = 0; b < 4; b++) {
      float z = BETA * ((lp[b] - lp[8 + b]) - (lp[b + 4] - lp[12 + b]));
      // -log_sigmoid(z) = softplus(-z), stable:
      float l = (z > 0.f) ? log1pf(expf(-z)) : (-z + log1pf(expf(z)));
      loss += l;
    }
    out[0] = loss / 4.f;
  }
}

extern "C" void kernel_launch(void* const* d_in, const int* in_sizes, int n_in,
                              void* d_out, int out_size, void* d_ws, size_t ws_size,
                              hipStream_t stream) {
  const float* x  = (const float*)d_in[0];
  const float* rx = (const float*)d_in[1];
  const int*   y  = (const int*)d_in[2];
  const float* W  = (const float*)d_in[3];
  const float* rW = (const float*)d_in[4];
  float* out = (float*)d_out;

  char* ws = (char*)d_ws;
  float* sumexp = (float*)ws;                 // 2*4096 fp32
  float* tgt    = (float*)(ws + 32 * 1024);   // 2*4096 fp32
  hipMemsetAsync(d_ws, 0, 64 * 1024, stream); // zero accumulators (ws is poisoned)

  const size_t XB_ELEMS = (size_t)NTOK * K_DIM;       // 8,388,608
  const size_t WB_ELEMS = (size_t)VOCAB * K_DIM;      // 65,536,000
  const size_t NEED = 64 * 1024 + 2 * (XB_ELEMS + WB_ELEMS);  // fp8: 1 B/elem

  if (ws_size >= NEED) {
    unsigned char* Xb  = (unsigned char*)(ws + 64 * 1024);
    unsigned char* rXb = Xb + XB_ELEMS;
    unsigned char* Wb  = rXb + XB_ELEMS;
    unsigned char* rWb = Wb + WB_ELEMS;
    cvt_all_fp8<<<dim3(8192, 4), 256, 0, stream>>>(x, rx, W, rW, Xb, rXb, Wb, rWb);
    // 256x128 tiles: (4096/256)*(32000/128) = 16*250 = 4000 tile-blocks, z = model
    gemm_lse_fp8<<<dim3(4000, 1, 2), 512, 0, stream>>>(Xb, rXb, Wb, rWb, sumexp);
  } else {
    gemm_lse_f32<<<dim3(32, 250, 2), 256, 0, stream>>>(x, rx, W, rW, sumexp);
  }

  tgt_kernel<<<2048, 256, 0, stream>>>(x, rx, W, rW, y, tgt);
  finalize<<<1, 256, 0, stream>>>(sumexp, tgt, y, out);
}